// Round 6
// baseline (339.726 us; speedup 1.0000x reference)
//
#include <hip/hip_runtime.h>
#include <hip/hip_bf16.h>
#include <math.h>

#define B_SZ 16
#define T_SZ 128
#define N_P 12
#define D_SZ 1024
#define D2_SZ 2048
#define BT 2048          // B*T tokens
#define KDIM 2048        // inner dim of projections (2D)
#define EALL 8192        // 4*1024 (tb,pb,ta,pa) + 2*2048 (gb,ga)
#define EPROJ 4096       // tb|pb|ta|pa row width
#define SPAD 136         // padded S row (128 + 8) to kill LDS bank conflicts

typedef __attribute__((ext_vector_type(8))) short short8;    // 8 bf16 = 4 VGPRs
typedef __attribute__((ext_vector_type(4))) float floatx4;   // MFMA C/D

__device__ inline void gload_lds16(const void* g, void* l) {
  __builtin_amdgcn_global_load_lds(
      (const __attribute__((address_space(1))) void*)g,
      (__attribute__((address_space(3))) void*)l, 16, 0, 0);
}

__device__ inline unsigned short f2bf(float x) {
  union { __hip_bfloat16 h; unsigned short u; } cv;
  cv.h = __float2bfloat16(x);
  return cv.u;
}
__device__ inline float bf2f(unsigned short u) {
  return __uint_as_float(((unsigned)u) << 16);
}

// ---------------------------------------------------------------------------
// Kernel 1: prep = build_n (blocks 0..2047) + all weight cvt (blocks 2048..14335)
// ---------------------------------------------------------------------------
__global__ __launch_bounds__(256) void prep_kernel(
    const float* __restrict__ feat, const float* __restrict__ Wq,
    const float* __restrict__ Wtb, const float* __restrict__ Wpb,
    const float* __restrict__ Wta, const float* __restrict__ Wpa,
    const float* __restrict__ Wgb, const float* __restrict__ Wga,
    unsigned short* __restrict__ Nbf, unsigned short* __restrict__ Wb) {
  const int bx = blockIdx.x;
  const int tid = threadIdx.x;

  if (bx < 2048) {
    // ---- build n = [g ; max] for token bx ----
    const int t = bx;
    const float4* fb4 = (const float4*)(feat + (size_t)t * N_P * D_SZ);
    const float4* wq4 = (const float4*)Wq;

    float4 q = {0.f, 0.f, 0.f, 0.f};
#pragma unroll
    for (int m = 0; m < N_P; ++m) {
      const float4 v = wq4[m * 256 + tid];
      q.x += v.x; q.y += v.y; q.z += v.z; q.w += v.w;
    }

    float4 fv[N_P];
    float part[N_P];
#pragma unroll
    for (int n = 0; n < N_P; ++n) {
      const float4 f = fb4[n * 256 + tid];
      fv[n] = f;
      part[n] = f.x * q.x + f.y * q.y + f.z * q.z + f.w * q.w;
    }

    __shared__ float wred[N_P * 4];
    const int lane = tid & 63;
    const int wave = tid >> 6;
#pragma unroll
    for (int n = 0; n < N_P; ++n) {
      float v = part[n];
#pragma unroll
      for (int off = 32; off; off >>= 1) v += __shfl_down(v, off);
      if (lane == 0) wred[n * 4 + wave] = v;
    }
    __syncthreads();

    float w[N_P];
#pragma unroll
    for (int n = 0; n < N_P; ++n)
      w[n] = wred[n * 4 + 0] + wred[n * 4 + 1] + wred[n * 4 + 2] + wred[n * 4 + 3];

    float4 g = {0.f, 0.f, 0.f, 0.f};
    float4 fm = {-INFINITY, -INFINITY, -INFINITY, -INFINITY};
#pragma unroll
    for (int n = 0; n < N_P; ++n) {
      const float4 f = fv[n];
      g.x += w[n] * f.x; g.y += w[n] * f.y; g.z += w[n] * f.z; g.w += w[n] * f.w;
      fm.x = fmaxf(fm.x, f.x); fm.y = fmaxf(fm.y, f.y);
      fm.z = fmaxf(fm.z, f.z); fm.w = fmaxf(fm.w, f.w);
    }
    ushort4 og, of;
    og.x = f2bf(g.x); og.y = f2bf(g.y); og.z = f2bf(g.z); og.w = f2bf(g.w);
    of.x = f2bf(fm.x); of.y = f2bf(fm.y); of.z = f2bf(fm.z); of.w = f2bf(fm.w);
    *(ushort4*)&Nbf[(size_t)t * D2_SZ + tid * 4] = og;
    *(ushort4*)&Nbf[(size_t)t * D2_SZ + D_SZ + tid * 4] = of;
  } else if (bx < 6144) {
    // ---- small weights tb,pb,ta,pa: 2 float4 per thread ----
    const int fi = (bx - 2048) * 256 + tid;   // [0, 1048576)
    const float* smalls[4] = {Wtb, Wpb, Wta, Wpa};
#pragma unroll
    for (int half = 0; half < 2; ++half) {
      const int v = fi + half * 1048576;
      const int w = v >> 19;          // 524288 float4 per small weight
      const int off = v & 524287;
      const float4 x = ((const float4*)smalls[w])[off];
      ushort4 o;
      o.x = f2bf(x.x); o.y = f2bf(x.y); o.z = f2bf(x.z); o.w = f2bf(x.w);
      ((ushort4*)Wb)[(size_t)w * 524288 + off] = o;
    }
  } else {
    // ---- g weights gb,ga: 1 float4 per thread ----
    const int gi = (bx - 6144) * 256 + tid;   // [0, 2097152)
    const int g = gi >> 20;                   // 1048576 float4 per g weight
    const int off = gi & 1048575;
    const float4 x = ((const float4*)(g ? Wga : Wgb))[off];
    ushort4 o;
    o.x = f2bf(x.x); o.y = f2bf(x.y); o.z = f2bf(x.z); o.w = f2bf(x.w);
    ((ushort4*)Wb)[2097152 + (size_t)g * 1048576 + off] = o;
  }
}

// ---------------------------------------------------------------------------
// Kernel 2: fused projection GEMM, bf16 MFMA, BK=64 (half the barriers).
// LDS slot (row, c) holds global chunk c ^ (row&7)  (conflict-free frag reads).
// 128x128 tile, 4 waves (2x2), 16x16x32 MFMA, width-16 global_load_lds.
// ---------------------------------------------------------------------------
__global__ __launch_bounds__(256) void gemm_fused(
    const unsigned short* __restrict__ X,
    const unsigned short* __restrict__ Wb,
    unsigned short* __restrict__ Cproj,
    unsigned short* __restrict__ Gbt,
    unsigned short* __restrict__ Gat) {
  __shared__ __align__(16) unsigned short As[128 * 64];
  __shared__ __align__(16) unsigned short Bs[128 * 64];
  const int tid = threadIdx.x;
  const int lane = tid & 63;
  const int w = tid >> 6;
  const int m0 = blockIdx.x * 128;
  const int e0 = blockIdx.y * 128;
  const int wm = (w >> 1) * 64;
  const int wn = (w & 1) * 64;
  const int quad = lane >> 4;
  const int l15 = lane & 15;

  floatx4 acc[4][4];
#pragma unroll
  for (int mt = 0; mt < 4; ++mt)
#pragma unroll
    for (int nt = 0; nt < 4; ++nt) {
      floatx4 z = {0.f, 0.f, 0.f, 0.f};
      acc[mt][nt] = z;
    }

  // staging: slot s = c*256+tid; row = s>>3 = c*32 + (tid>>3); store col = s&7 = tid&7
  // global chunk = (tid&7) ^ (row&7) = (tid&7) ^ ((tid>>3)&7)  (c-independent)
  const int r0 = tid >> 3;                      // 0..31
  const int cglob = (tid & 7) ^ (r0 & 7);
  const unsigned short* gA0 = X + (size_t)(m0 + r0) * KDIM + cglob * 8;
  const unsigned short* gB0 = Wb + (size_t)(e0 + r0) * KDIM + cglob * 8;

  // fragment chunk (same for A and B since wm,wn are multiples of 8):
  const int ch0 = quad ^ (l15 & 7);             // k-half 0
  const int ch1 = (quad + 4) ^ (l15 & 7);       // k-half 1

  for (int k0 = 0; k0 < KDIM; k0 += 64) {
#pragma unroll
    for (int c = 0; c < 4; ++c) {
      gload_lds16(gA0 + k0 + (size_t)c * 32 * KDIM, &As[(size_t)(w * 64 + c * 256) * 8]);
      gload_lds16(gB0 + k0 + (size_t)c * 32 * KDIM, &Bs[(size_t)(w * 64 + c * 256) * 8]);
    }
    __syncthreads();
#pragma unroll
    for (int h = 0; h < 2; ++h) {
      const int ch = h ? ch1 : ch0;
      short8 a[4], b[4];
#pragma unroll
      for (int mt = 0; mt < 4; ++mt)
        a[mt] = *(const short8*)&As[(wm + mt * 16 + l15) * 64 + ch * 8];
#pragma unroll
      for (int nt = 0; nt < 4; ++nt)
        b[nt] = *(const short8*)&Bs[(wn + nt * 16 + l15) * 64 + ch * 8];
#pragma unroll
      for (int mt = 0; mt < 4; ++mt)
#pragma unroll
        for (int nt = 0; nt < 4; ++nt)
          acc[mt][nt] = __builtin_amdgcn_mfma_f32_16x16x32_bf16(
              a[mt], b[nt], acc[mt][nt], 0, 0, 0);
    }
    __syncthreads();
  }

  if (blockIdx.y < 32) {
#pragma unroll
    for (int mt = 0; mt < 4; ++mt)
#pragma unroll
      for (int nt = 0; nt < 4; ++nt) {
        const int col = e0 + wn + nt * 16 + l15;
#pragma unroll
        for (int r = 0; r < 4; ++r) {
          const int rowg = m0 + wm + mt * 16 + quad * 4 + r;
          Cproj[(size_t)rowg * EPROJ + col] = f2bf(acc[mt][nt][r]);
        }
      }
  } else {
    unsigned short* Gt = (blockIdx.y < 48) ? Gbt : Gat;
    const int fb = e0 - ((blockIdx.y < 48) ? 4096 : 6144);
#pragma unroll
    for (int mt = 0; mt < 4; ++mt)
#pragma unroll
      for (int nt = 0; nt < 4; ++nt) {
        const int f = fb + wn + nt * 16 + l15;
        const int tok0 = m0 + wm + mt * 16 + quad * 4;
        ushort4 o;
        o.x = f2bf(acc[mt][nt][0]); o.y = f2bf(acc[mt][nt][1]);
        o.z = f2bf(acc[mt][nt][2]); o.w = f2bf(acc[mt][nt][3]);
        *(ushort4*)&Gt[(size_t)f * BT + tok0] = o;
      }
  }
}

// ---------------------------------------------------------------------------
// Kernel 3: score partials via MFMA. grid (16 batches, 2 branches, 4 K-chunks).
// Spart[(br*16+b)*4+kc][i][j] (fp32, unmasked, unscaled). BK=32 + XOR swizzle.
// ---------------------------------------------------------------------------
__global__ __launch_bounds__(256) void score_kernel(
    const unsigned short* __restrict__ Cproj, float* __restrict__ Spart) {
  const int b = blockIdx.x;
  const int br = blockIdx.y;
  const int kc = blockIdx.z;
  const int aoff = br ? 2048 : 0;   // ta : tb
  const int boff = aoff + 1024;     // pa : pb

  __shared__ __align__(16) unsigned short As[128 * 32];
  __shared__ __align__(16) unsigned short Bs[128 * 32];
  const int tid = threadIdx.x;
  const int lane = tid & 63;
  const int w = tid >> 6;
  const int wm = (w >> 1) * 64;
  const int wn = (w & 1) * 64;
  const int quad = lane >> 4;
  const int l15 = lane & 15;
  const int t0 = b * T_SZ;

  floatx4 acc[4][4];
#pragma unroll
  for (int mt = 0; mt < 4; ++mt)
#pragma unroll
    for (int nt = 0; nt < 4; ++nt) {
      floatx4 z = {0.f, 0.f, 0.f, 0.f};
      acc[mt][nt] = z;
    }

  const unsigned short* gA[2];
  const unsigned short* gB[2];
  unsigned short* lA[2];
  unsigned short* lB[2];
#pragma unroll
  for (int c = 0; c < 2; ++c) {
    const int s = w * 64 + lane + c * 256;
    const int row = s >> 2;
    const int ccg = (s & 3) ^ ((row >> 1) & 3);
    gA[c] = Cproj + (size_t)(t0 + row) * EPROJ + aoff + ccg * 8;
    gB[c] = Cproj + (size_t)(t0 + row) * EPROJ + boff + ccg * 8;
    lA[c] = &As[(size_t)s * 8];
    lB[c] = &Bs[(size_t)s * 8];
  }

  int aofs[4], bofs[4];
#pragma unroll
  for (int mt = 0; mt < 4; ++mt) {
    const int row = wm + mt * 16 + l15;
    aofs[mt] = row * 32 + ((quad ^ ((row >> 1) & 3)) * 8);
  }
#pragma unroll
  for (int nt = 0; nt < 4; ++nt) {
    const int row = wn + nt * 16 + l15;
    bofs[nt] = row * 32 + ((quad ^ ((row >> 1) & 3)) * 8);
  }

  const int kbeg = kc * 256;
  for (int k0 = kbeg; k0 < kbeg + 256; k0 += 32) {
#pragma unroll
    for (int c = 0; c < 2; ++c) {
      gload_lds16(gA[c] + k0, lA[c]);
      gload_lds16(gB[c] + k0, lB[c]);
    }
    __syncthreads();
    short8 a[4], bb[4];
#pragma unroll
    for (int mt = 0; mt < 4; ++mt) a[mt] = *(const short8*)&As[aofs[mt]];
#pragma unroll
    for (int nt = 0; nt < 4; ++nt) bb[nt] = *(const short8*)&Bs[bofs[nt]];
#pragma unroll
    for (int mt = 0; mt < 4; ++mt)
#pragma unroll
      for (int nt = 0; nt < 4; ++nt)
        acc[mt][nt] = __builtin_amdgcn_mfma_f32_16x16x32_bf16(
            a[mt], bb[nt], acc[mt][nt], 0, 0, 0);
    __syncthreads();
  }

  float* Sp = Spart + ((size_t)(br * B_SZ + b) * 4 + kc) * T_SZ * T_SZ;
#pragma unroll
  for (int mt = 0; mt < 4; ++mt)
#pragma unroll
    for (int nt = 0; nt < 4; ++nt) {
      const int j = wn + nt * 16 + l15;
#pragma unroll
      for (int r = 0; r < 4; ++r) {
        const int i = wm + mt * 16 + quad * 4 + r;
        Sp[(size_t)i * T_SZ + j] = acc[mt][nt][r];
      }
    }
}

// ---------------------------------------------------------------------------
// Kernel 4: fused combine + PV MFMA.
// Per block (ft, b): reduce Spart -> masked/scaled bf16 S in LDS, then
// out[t0+i][f0+f] = n + Sb·Gbt + Sa·Gat  (A-frags from LDS, B-frags global).
// ---------------------------------------------------------------------------
__global__ __launch_bounds__(256) void pv_fused(
    const unsigned short* __restrict__ Nbf,
    const float* __restrict__ Spart,
    const unsigned short* __restrict__ Gbt,
    const unsigned short* __restrict__ Gat,
    float* __restrict__ out) {
  const int ft = blockIdx.x;
  const int b = blockIdx.y;
  const int f0 = ft * 128;
  const int t0 = b * T_SZ;
  const int tid = threadIdx.x;
  const float scale = 0.022097086912079608f;  // 1/sqrt(2*1024)

  __shared__ __align__(16) unsigned short Sl[2][128 * SPAD];

  // ---- combine: thread owns row (br, i) ----
  {
    const int br = tid >> 7;
    const int i = tid & 127;
    const float* Sp = Spart + ((size_t)(br * B_SZ + b) * 4) * (T_SZ * T_SZ) +
                      (size_t)i * T_SZ;
#pragma unroll
    for (int j4 = 0; j4 < 32; ++j4) {
      float4 s = {0.f, 0.f, 0.f, 0.f};
#pragma unroll
      for (int kc = 0; kc < 4; ++kc) {
        const float4 v = *(const float4*)&Sp[(size_t)kc * T_SZ * T_SZ + j4 * 4];
        s.x += v.x; s.y += v.y; s.z += v.z; s.w += v.w;
      }
      const int j0 = j4 * 4;
      ushort4 o;
      o.x = f2bf((br ? (j0 + 0 > i) : (j0 + 0 < i)) ? s.x * scale : 0.f);
      o.y = f2bf((br ? (j0 + 1 > i) : (j0 + 1 < i)) ? s.y * scale : 0.f);
      o.z = f2bf((br ? (j0 + 2 > i) : (j0 + 2 < i)) ? s.z * scale : 0.f);
      o.w = f2bf((br ? (j0 + 3 > i) : (j0 + 3 < i)) ? s.w * scale : 0.f);
      *(ushort4*)&Sl[br][i * SPAD + j0] = o;
    }
  }
  __syncthreads();

  // ---- PV MFMA ----
  const int lane = tid & 63;
  const int w = tid >> 6;
  const int wm = (w >> 1) * 64;   // token dim
  const int wn = (w & 1) * 64;    // f dim
  const int quad = lane >> 4;
  const int l15 = lane & 15;

  floatx4 acc[4][4];
#pragma unroll
  for (int mt = 0; mt < 4; ++mt)
#pragma unroll
    for (int nt = 0; nt < 4; ++nt) {
      floatx4 z = {0.f, 0.f, 0.f, 0.f};
      acc[mt][nt] = z;
    }

#pragma unroll
  for (int k0 = 0; k0 < T_SZ; k0 += 32) {
    short8 ab[4], aa[4], bb[4], ba[4];
#pragma unroll
    for (int mt = 0; mt < 4; ++mt) {
      const int i = wm + mt * 16 + l15;
      ab[mt] = *(const short8*)&Sl[0][i * SPAD + k0 + quad * 8];
      aa[mt] = *(const short8*)&Sl[1][i * SPAD + k0 + quad * 8];
    }
#pragma unroll
    for (int nt = 0; nt < 4; ++nt) {
      const int f = f0 + wn + nt * 16 + l15;
      bb[nt] = *(const short8*)&Gbt[(size_t)f * BT + t0 + k0 + quad * 8];
      ba[nt] = *(const short8*)&Gat[(size_t)f * BT + t0 + k0 + quad * 8];
    }
#pragma unroll
    for (int mt = 0; mt < 4; ++mt)
#pragma unroll
      for (int nt = 0; nt < 4; ++nt) {
        acc[mt][nt] = __builtin_amdgcn_mfma_f32_16x16x32_bf16(
            ab[mt], bb[nt], acc[mt][nt], 0, 0, 0);
        acc[mt][nt] = __builtin_amdgcn_mfma_f32_16x16x32_bf16(
            aa[mt], ba[nt], acc[mt][nt], 0, 0, 0);
      }
  }

#pragma unroll
  for (int mt = 0; mt < 4; ++mt)
#pragma unroll
    for (int nt = 0; nt < 4; ++nt) {
      const int f = f0 + wn + nt * 16 + l15;
#pragma unroll
      for (int r = 0; r < 4; ++r) {
        const int tok = t0 + wm + mt * 16 + quad * 4 + r;
        out[(size_t)tok * D2_SZ + f] =
            acc[mt][nt][r] + bf2f(Nbf[(size_t)tok * D2_SZ + f]);
      }
    }
}

// ---------------------------------------------------------------------------
extern "C" void kernel_launch(void* const* d_in, const int* in_sizes, int n_in,
                              void* d_out, int out_size, void* d_ws, size_t ws_size,
                              hipStream_t stream) {
  const float* feat = (const float*)d_in[0];
  const float* Wq  = (const float*)d_in[1];
  const float* Wtb = (const float*)d_in[2];
  const float* Wpb = (const float*)d_in[3];
  const float* Wgb = (const float*)d_in[4];  // dict order: gb before ta
  const float* Wta = (const float*)d_in[5];
  const float* Wpa = (const float*)d_in[6];
  const float* Wga = (const float*)d_in[7];
  float* out = (float*)d_out;

  unsigned short* ws = (unsigned short*)d_ws;
  unsigned short* Nbf   = ws;                                 // [2048][2048] bf16
  unsigned short* Wb    = Nbf + (size_t)BT * D2_SZ;           // [8192][2048] bf16
  unsigned short* Cproj = Wb + (size_t)EALL * KDIM;           // [2048][4096] bf16
  unsigned short* Gbt   = Cproj + (size_t)BT * EPROJ;         // [2048][2048] bf16
  unsigned short* Gat   = Gbt + (size_t)D2_SZ * BT;           // [2048][2048] bf16
  float* Spart = (float*)(Gat + (size_t)D2_SZ * BT);          // [2][16][4][128][128] f32

  prep_kernel<<<14336, 256, 0, stream>>>(feat, Wq, Wtb, Wpb, Wta, Wpa, Wgb, Wga,
                                         Nbf, Wb);
  gemm_fused<<<dim3(BT / 128, EALL / 128), 256, 0, stream>>>(Nbf, Wb, Cproj, Gbt, Gat);
  score_kernel<<<dim3(B_SZ, 2, 4), 256, 0, stream>>>(Cproj, Spart);
  pv_fused<<<dim3(D2_SZ / 128, B_SZ), 256, 0, stream>>>(Nbf, Spart, Gbt, Gat, out);
}